// Round 5
// baseline (309.400 us; speedup 1.0000x reference)
//
#include <hip/hip_runtime.h>

#define H 768
#define W 768
#define SW 256        // output cols per strip
#define RW 272        // region width (SW + 16)
#define ABW 264       // A,b row width (SW + 8)
#define ROWS 48       // output rows per band
#define NSTEP 32      // (ROWS + 16) / 2 double-row steps
#define RADIUS 4

__global__ __launch_bounds__(256, 5) void gf_stream3(
    const float* __restrict__ xg, const float* __restrict__ yg,
    float* __restrict__ outg)
{
    // 2 rows packed per float4 -> one b128 tap serves both rows.
    __shared__ float4 xybuf[2][RW];   // (x0,y0,x1,y1)   8704 B
    __shared__ float4 abbuf[2][ABW];  // (A0,B0,A1,B1)   8448 B
    __shared__ float4 tring[9][8];    // extra-col h-ring 1152 B   (18304 B total)

    const int t     = threadIdx.x;
    const int base  = blockIdx.x * SW;
    const int R0    = blockIdx.y * ROWS;
    const int plane = blockIdx.z;

    const float* xp = xg + (size_t)plane * (H * W);
    const float* yp = yg + (size_t)plane * (H * W);
    float*       op = outg + (size_t)plane * (H * W);

    // ---- per-thread column geometry (loop-invariant) ----
    const int  a_abs   = base + t - 4;                  // main A-col
    const bool a_colok = (a_abs >= 0) && (a_abs < W);
    const float invCwA = a_colok
        ? 1.0f / (float)(min(a_abs + RADIUS, W - 1) - max(a_abs - RADIUS, 0) + 1) : 0.f;
    const int  a2_abs   = base + 252 + t;               // extra A-col (t<8)
    const bool a2_colok = (t < 8) && (a2_abs < W);
    const float invCwA2 = a2_colok
        ? 1.0f / (float)(min(a2_abs + RADIUS, W - 1) - max(a2_abs - RADIUS, 0) + 1) : 0.f;
    const int   c_abs  = base + t;                      // output col
    const float invCwO = 1.0f / (float)(min(c_abs + RADIUS, W - 1) - max(c_abs - RADIUS, 0) + 1);
    const int  lc1   = base + t - 8;                    // load col (region col t)
    const bool lc1ok = (lc1 >= 0) && (lc1 < W);
    const int  lc2   = base + 248 + t;                  // load col (region col 256+t), t<16
    const bool lc2ok = (t < 16) && (lc2 < W);

    // ---- register rings, all statically indexed via the 9-unroll ----
    float hx[9], hy[9], hxy[9], hxx[9];   // h-sums history (col a_abs)
    float hA9[9], hB9[9];                 // h-sums of A,b history (col c_abs)
    float xdel[9];                        // delayed x at output col (delay 8/9 rows)
#pragma unroll
    for (int i = 0; i < 9; ++i) { hx[i]=hy[i]=hxy[i]=hxx[i]=0.f; hA9[i]=hB9[i]=0.f; xdel[i]=0.f; }
    float vx=0.f, vy=0.f, vxy=0.f, vxx=0.f;       // vertical sums (col a_abs)
    float v2x=0.f, v2y=0.f, v2xy=0.f, v2xx=0.f;   // vertical sums (extra col)
    float vA=0.f, vB=0.f;                         // vertical sums of hA,hB

    if (t < 72) ((float4*)tring)[t] = make_float4(0.f,0.f,0.f,0.f);

    // ---- prologue: xybuf[0] <- rows R0-8, R0-7 ; prefetch rows R0-6, R0-5 ----
    {
        int g0 = R0 - 8, g1 = R0 - 7;
        bool k0 = (g0 >= 0), k1 = (g1 >= 0);
        const float *x0 = xp + g0 * W, *y0 = yp + g0 * W;
        const float *x1 = xp + g1 * W, *y1 = yp + g1 * W;
        float a0 = (k0 && lc1ok) ? x0[lc1] : 0.f, b0 = (k0 && lc1ok) ? y0[lc1] : 0.f;
        float a1 = (k1 && lc1ok) ? x1[lc1] : 0.f, b1 = (k1 && lc1ok) ? y1[lc1] : 0.f;
        xybuf[0][t] = make_float4(a0, b0, a1, b1);
        if (t < 16) {
            float c0 = (k0 && lc2ok) ? x0[lc2] : 0.f, d0 = (k0 && lc2ok) ? y0[lc2] : 0.f;
            float c1 = (k1 && lc2ok) ? x1[lc2] : 0.f, d1 = (k1 && lc2ok) ? y1[lc2] : 0.f;
            xybuf[0][256 + t] = make_float4(c0, d0, c1, d1);
        }
    }
    float p0x, p0y, p0x2, p0y2, p1x, p1y, p1x2, p1y2;
    {
        int g0 = R0 - 6, g1 = R0 - 5;
        bool k0 = (g0 >= 0), k1 = (g1 >= 0);
        const float *x0 = xp + g0 * W, *y0 = yp + g0 * W;
        const float *x1 = xp + g1 * W, *y1 = yp + g1 * W;
        p0x  = (k0 && lc1ok) ? x0[lc1] : 0.f;  p0y  = (k0 && lc1ok) ? y0[lc1] : 0.f;
        p1x  = (k1 && lc1ok) ? x1[lc1] : 0.f;  p1y  = (k1 && lc1ok) ? y1[lc1] : 0.f;
        p0x2 = (k0 && lc2ok) ? x0[lc2] : 0.f;  p0y2 = (k0 && lc2ok) ? y0[lc2] : 0.f;
        p1x2 = (k1 && lc2ok) ? x1[lc2] : 0.f;  p1y2 = (k1 && lc2ok) ? y1[lc2] : 0.f;
    }
    __syncthreads();

    for (int S0 = 0; S0 < NSTEP; S0 += 9) {
#pragma unroll
        for (int u = 0; u < 9; ++u) {
            const int S = S0 + u;
            if (S < NSTEP) {
                const int r0  = R0 - 16 + 2 * S;    // output row j=0 this step
                const int cur = S & 1, nxt = cur ^ 1;
                const int s0 = (2 * u) % 9, s1 = (2 * u + 1) % 9;  // static slots

                // delayed-x reads (slot s1 is overwritten below; read first)
                const float xq0 = xdel[(2 * u + 1) % 9];   // x(r0,   c_abs)
                const float xq1 = xdel[(2 * u + 2) % 9];   // x(r0+1, c_abs)

                // -- publish rows r0+10, r0+11 (prefetched last step) --
                xybuf[nxt][t] = make_float4(p0x, p0y, p1x, p1y);
                if (t < 16) xybuf[nxt][256 + t] = make_float4(p0x2, p0y2, p1x2, p1y2);

                // -- prefetch rows r0+12, r0+13 --
                {
                    int g0 = r0 + 12, g1 = r0 + 13;
                    bool k0 = (g0 >= 0) && (g0 < H);
                    bool k1 = (g1 >= 0) && (g1 < H);
                    const float *x0 = xp + g0 * W, *y0 = yp + g0 * W;
                    const float *x1 = xp + g1 * W, *y1 = yp + g1 * W;
                    p0x  = (k0 && lc1ok) ? x0[lc1] : 0.f;  p0y  = (k0 && lc1ok) ? y0[lc1] : 0.f;
                    p1x  = (k1 && lc1ok) ? x1[lc1] : 0.f;  p1y  = (k1 && lc1ok) ? y1[lc1] : 0.f;
                    p0x2 = (k0 && lc2ok) ? x0[lc2] : 0.f;  p0y2 = (k0 && lc2ok) ? y0[lc2] : 0.f;
                    p1x2 = (k1 && lc2ok) ? x1[lc2] : 0.f;  p1y2 = (k1 && lc2ok) ? y1[lc2] : 0.f;
                }

                // -- NH: 9 b128 taps -> h-sums for both rows --
                float nx0=0.f,ny0=0.f,nxy0=0.f,nxx0=0.f;
                float nx1=0.f,ny1=0.f,nxy1=0.f,nxx1=0.f;
                float4 tap;
#pragma unroll
                for (int d = 0; d < 9; ++d) {
                    tap = xybuf[cur][t + d];
                    nx0 += tap.x; ny0 += tap.y; nxy0 += tap.x * tap.y; nxx0 += tap.x * tap.x;
                    nx1 += tap.z; ny1 += tap.w; nxy1 += tap.z * tap.w; nxx1 += tap.z * tap.z;
                }
                // tap==taps[8] is region col t+8 == output col c_abs
                xdel[s0] = tap.x;   // x(r0+8, c_abs)
                xdel[s1] = tap.z;   // x(r0+9, c_abs)

                // -- row0 vertical ring + A,b --
                vx  += nx0  - hx[s0];  hx[s0]  = nx0;
                vy  += ny0  - hy[s0];  hy[s0]  = ny0;
                vxy += nxy0 - hxy[s0]; hxy[s0] = nxy0;
                vxx += nxx0 - hxx[s0]; hxx[s0] = nxx0;
                float A0 = 0.f, B0 = 0.f;
                const int ra0 = r0 + 4;
                if (S >= 4 && a_colok && ra0 >= 0 && ra0 < H) {
                    const float invCh = 1.0f /
                        (float)(min(ra0 + RADIUS, H - 1) - max(ra0 - RADIUS, 0) + 1);
                    float invN = invCh * invCwA;
                    float mx = vx * invN, my = vy * invN;
                    float cov = vxy * invN - mx * my;
                    float vr  = vxx * invN - mx * mx;
                    A0 = cov * __builtin_amdgcn_rcpf(vr + 0.1f);
                    B0 = my - A0 * mx;
                }
                // -- row1 vertical ring + A,b --
                vx  += nx1  - hx[s1];  hx[s1]  = nx1;
                vy  += ny1  - hy[s1];  hy[s1]  = ny1;
                vxy += nxy1 - hxy[s1]; hxy[s1] = nxy1;
                vxx += nxx1 - hxx[s1]; hxx[s1] = nxx1;
                float A1 = 0.f, B1 = 0.f;
                const int ra1 = r0 + 5;
                if (S >= 4 && a_colok && ra1 >= 0 && ra1 < H) {
                    const float invCh = 1.0f /
                        (float)(min(ra1 + RADIUS, H - 1) - max(ra1 - RADIUS, 0) + 1);
                    float invN = invCh * invCwA;
                    float mx = vx * invN, my = vy * invN;
                    float cov = vxy * invN - mx * my;
                    float vr  = vxx * invN - mx * mx;
                    A1 = cov * __builtin_amdgcn_rcpf(vr + 0.1f);
                    B1 = my - A1 * mx;
                }
                if (S >= 4) abbuf[cur][t] = make_float4(A0, B0, A1, B1);

                // -- extra A-cols (region 260..267), lanes t<8, same-lane RMW ring --
                if (t < 8) {
                    float ex0=0.f,ey0=0.f,exy0=0.f,exx0=0.f;
                    float ex1=0.f,ey1=0.f,exy1=0.f,exx1=0.f;
#pragma unroll
                    for (int d = 0; d < 9; ++d) {
                        float4 v = xybuf[cur][256 + t + d];
                        ex0 += v.x; ey0 += v.y; exy0 += v.x * v.y; exx0 += v.x * v.x;
                        ex1 += v.z; ey1 += v.w; exy1 += v.z * v.w; exx1 += v.z * v.z;
                    }
                    float4 o0 = tring[s0][t];
                    v2x += ex0 - o0.x; v2y += ey0 - o0.y; v2xy += exy0 - o0.z; v2xx += exx0 - o0.w;
                    tring[s0][t] = make_float4(ex0, ey0, exy0, exx0);
                    float A20 = 0.f, B20 = 0.f;
                    if (S >= 4 && a2_colok && ra0 >= 0 && ra0 < H) {
                        const float invCh = 1.0f /
                            (float)(min(ra0 + RADIUS, H - 1) - max(ra0 - RADIUS, 0) + 1);
                        float invN = invCh * invCwA2;
                        float mx = v2x * invN, my = v2y * invN;
                        float cov = v2xy * invN - mx * my;
                        float vr  = v2xx * invN - mx * mx;
                        A20 = cov * __builtin_amdgcn_rcpf(vr + 0.1f);
                        B20 = my - A20 * mx;
                    }
                    float4 o1 = tring[s1][t];
                    v2x += ex1 - o1.x; v2y += ey1 - o1.y; v2xy += exy1 - o1.z; v2xx += exx1 - o1.w;
                    tring[s1][t] = make_float4(ex1, ey1, exy1, exx1);
                    float A21 = 0.f, B21 = 0.f;
                    if (S >= 4 && a2_colok && ra1 >= 0 && ra1 < H) {
                        const float invCh = 1.0f /
                            (float)(min(ra1 + RADIUS, H - 1) - max(ra1 - RADIUS, 0) + 1);
                        float invN = invCh * invCwA2;
                        float mx = v2x * invN, my = v2y * invN;
                        float cov = v2xy * invN - mx * my;
                        float vr  = v2xx * invN - mx * mx;
                        A21 = cov * __builtin_amdgcn_rcpf(vr + 0.1f);
                        B21 = my - A21 * mx;
                    }
                    if (S >= 4) abbuf[cur][256 + t] = make_float4(A20, B20, A21, B21);
                }

                __syncthreads();   // single barrier per step

                // -- O: 9 b128 taps of A,b -> both output rows --
                if (S >= 4) {
                    float hA0=0.f,hB0=0.f,hA1=0.f,hB1=0.f;
#pragma unroll
                    for (int d = 0; d < 9; ++d) {
                        float4 v = abbuf[cur][t + d];
                        hA0 += v.x; hB0 += v.y; hA1 += v.z; hB1 += v.w;
                    }
                    vA += hA0 - hA9[s0]; hA9[s0] = hA0;
                    vB += hB0 - hB9[s0]; hB9[s0] = hB0;
                    if (S >= 8) {
                        const float invCh = 1.0f /
                            (float)(min(r0 + RADIUS, H - 1) - max(r0 - RADIUS, 0) + 1);
                        float invN = invCh * invCwO;
                        op[r0 * W + c_abs] = (vA * invN) * xq0 + (vB * invN);
                    }
                    vA += hA1 - hA9[s1]; hA9[s1] = hA1;
                    vB += hB1 - hB9[s1]; hB9[s1] = hB1;
                    if (S >= 8) {
                        const int r = r0 + 1;
                        const float invCh = 1.0f /
                            (float)(min(r + RADIUS, H - 1) - max(r - RADIUS, 0) + 1);
                        float invN = invCh * invCwO;
                        op[r * W + c_abs] = (vA * invN) * xq1 + (vB * invN);
                    }
                }
            }
        }
    }
}

extern "C" void kernel_launch(void* const* d_in, const int* in_sizes, int n_in,
                              void* d_out, int out_size, void* d_ws, size_t ws_size,
                              hipStream_t stream) {
    const float* x = (const float*)d_in[0];
    const float* y = (const float*)d_in[1];
    float* out = (float*)d_out;

    dim3 grid(W / SW, H / ROWS, 24);   // 3 x 16 x 24 = 1152 blocks (~4.5/CU, all resident)
    dim3 block(256);
    hipLaunchKernelGGL(gf_stream3, grid, block, 0, stream, x, y, out);
}

// Round 6
// 251.625 us; speedup vs baseline: 1.2296x; 1.2296x over previous
//
#include <hip/hip_runtime.h>

#define H 768
#define W 768
#define SW 256        // output cols per strip
#define RW 272        // region width (SW + 16)
#define ABW 264       // A,b row width (SW + 8)
#define ROWS 48       // output rows per band
#define NSTEP 32      // (ROWS + 16) / 2 double-row steps
#define RADIUS 4

// NOTE: (256,4) not (256,5) — the 5-wave cap (~102 VGPR) spilled the register
// rings to scratch (WRITE_SIZE 112->669 MB, 3x slowdown). Live set is ~110 VGPR.
__global__ __launch_bounds__(256, 4) void gf_stream4(
    const float* __restrict__ xg, const float* __restrict__ yg,
    float* __restrict__ outg)
{
    // 2 rows packed per float4 -> one b128 tap serves both rows.
    __shared__ float4 xybuf[2][RW];   // (x0,y0,x1,y1)   8704 B
    __shared__ float4 abbuf[2][ABW];  // (A0,B0,A1,B1)   8448 B
    __shared__ float4 tring[9][8];    // extra-col h-ring 1152 B   (18304 B total)

    const int t     = threadIdx.x;
    const int base  = blockIdx.x * SW;
    const int R0    = blockIdx.y * ROWS;
    const int plane = blockIdx.z;

    const float* xp = xg + (size_t)plane * (H * W);
    const float* yp = yg + (size_t)plane * (H * W);
    float*       op = outg + (size_t)plane * (H * W);

    // ---- per-thread column geometry (loop-invariant) ----
    const int  a_abs   = base + t - 4;                  // main A-col
    const bool a_colok = (a_abs >= 0) && (a_abs < W);
    const float invCwA = a_colok
        ? 1.0f / (float)(min(a_abs + RADIUS, W - 1) - max(a_abs - RADIUS, 0) + 1) : 0.f;
    const int  a2_abs   = base + 252 + t;               // extra A-col (t<8)
    const bool a2_colok = (t < 8) && (a2_abs < W);
    const float invCwA2 = a2_colok
        ? 1.0f / (float)(min(a2_abs + RADIUS, W - 1) - max(a2_abs - RADIUS, 0) + 1) : 0.f;
    const int   c_abs  = base + t;                      // output col
    const float invCwO = 1.0f / (float)(min(c_abs + RADIUS, W - 1) - max(c_abs - RADIUS, 0) + 1);
    const int  lc1   = base + t - 8;                    // load col (region col t)
    const bool lc1ok = (lc1 >= 0) && (lc1 < W);
    const int  lc2   = base + 248 + t;                  // load col (region col 256+t), t<16
    const bool lc2ok = (t < 16) && (lc2 < W);

    // ---- register rings, all statically indexed via the 9-unroll ----
    float hx[9], hy[9], hxy[9], hxx[9];   // h-sums history (col a_abs)
    float hA9[9], hB9[9];                 // h-sums of A,b history (col c_abs)
    float xdel[9];                        // delayed x at output col (delay 8/9 rows)
#pragma unroll
    for (int i = 0; i < 9; ++i) { hx[i]=hy[i]=hxy[i]=hxx[i]=0.f; hA9[i]=hB9[i]=0.f; xdel[i]=0.f; }
    float vx=0.f, vy=0.f, vxy=0.f, vxx=0.f;       // vertical sums (col a_abs)
    float v2x=0.f, v2y=0.f, v2xy=0.f, v2xx=0.f;   // vertical sums (extra col)
    float vA=0.f, vB=0.f;                         // vertical sums of hA,hB

    if (t < 72) ((float4*)tring)[t] = make_float4(0.f,0.f,0.f,0.f);

    // ---- prologue: xybuf[0] <- rows R0-8, R0-7 ; prefetch rows R0-6, R0-5 ----
    {
        int g0 = R0 - 8, g1 = R0 - 7;
        bool k0 = (g0 >= 0), k1 = (g1 >= 0);
        const float *x0 = xp + g0 * W, *y0 = yp + g0 * W;
        const float *x1 = xp + g1 * W, *y1 = yp + g1 * W;
        float a0 = (k0 && lc1ok) ? x0[lc1] : 0.f, b0 = (k0 && lc1ok) ? y0[lc1] : 0.f;
        float a1 = (k1 && lc1ok) ? x1[lc1] : 0.f, b1 = (k1 && lc1ok) ? y1[lc1] : 0.f;
        xybuf[0][t] = make_float4(a0, b0, a1, b1);
        if (t < 16) {
            float c0 = (k0 && lc2ok) ? x0[lc2] : 0.f, d0 = (k0 && lc2ok) ? y0[lc2] : 0.f;
            float c1 = (k1 && lc2ok) ? x1[lc2] : 0.f, d1 = (k1 && lc2ok) ? y1[lc2] : 0.f;
            xybuf[0][256 + t] = make_float4(c0, d0, c1, d1);
        }
    }
    float p0x, p0y, p0x2, p0y2, p1x, p1y, p1x2, p1y2;
    {
        int g0 = R0 - 6, g1 = R0 - 5;
        bool k0 = (g0 >= 0), k1 = (g1 >= 0);
        const float *x0 = xp + g0 * W, *y0 = yp + g0 * W;
        const float *x1 = xp + g1 * W, *y1 = yp + g1 * W;
        p0x  = (k0 && lc1ok) ? x0[lc1] : 0.f;  p0y  = (k0 && lc1ok) ? y0[lc1] : 0.f;
        p1x  = (k1 && lc1ok) ? x1[lc1] : 0.f;  p1y  = (k1 && lc1ok) ? y1[lc1] : 0.f;
        p0x2 = (k0 && lc2ok) ? x0[lc2] : 0.f;  p0y2 = (k0 && lc2ok) ? y0[lc2] : 0.f;
        p1x2 = (k1 && lc2ok) ? x1[lc2] : 0.f;  p1y2 = (k1 && lc2ok) ? y1[lc2] : 0.f;
    }
    __syncthreads();

    for (int S0 = 0; S0 < NSTEP; S0 += 9) {
#pragma unroll
        for (int u = 0; u < 9; ++u) {
            const int S = S0 + u;
            if (S < NSTEP) {
                const int r0  = R0 - 16 + 2 * S;    // output row j=0 this step
                const int cur = S & 1, nxt = cur ^ 1;
                const int s0 = (2 * u) % 9, s1 = (2 * u + 1) % 9;  // static slots

                // delayed-x reads (slot s1 is overwritten below; read first)
                const float xq0 = xdel[(2 * u + 1) % 9];   // x(r0,   c_abs)
                const float xq1 = xdel[(2 * u + 2) % 9];   // x(r0+1, c_abs)

                // -- publish rows r0+10, r0+11 (prefetched last step) --
                xybuf[nxt][t] = make_float4(p0x, p0y, p1x, p1y);
                if (t < 16) xybuf[nxt][256 + t] = make_float4(p0x2, p0y2, p1x2, p1y2);

                // -- prefetch rows r0+12, r0+13 --
                {
                    int g0 = r0 + 12, g1 = r0 + 13;
                    bool k0 = (g0 >= 0) && (g0 < H);
                    bool k1 = (g1 >= 0) && (g1 < H);
                    const float *x0 = xp + g0 * W, *y0 = yp + g0 * W;
                    const float *x1 = xp + g1 * W, *y1 = yp + g1 * W;
                    p0x  = (k0 && lc1ok) ? x0[lc1] : 0.f;  p0y  = (k0 && lc1ok) ? y0[lc1] : 0.f;
                    p1x  = (k1 && lc1ok) ? x1[lc1] : 0.f;  p1y  = (k1 && lc1ok) ? y1[lc1] : 0.f;
                    p0x2 = (k0 && lc2ok) ? x0[lc2] : 0.f;  p0y2 = (k0 && lc2ok) ? y0[lc2] : 0.f;
                    p1x2 = (k1 && lc2ok) ? x1[lc2] : 0.f;  p1y2 = (k1 && lc2ok) ? y1[lc2] : 0.f;
                }

                // -- NH: 9 b128 taps -> h-sums for both rows --
                float nx0=0.f,ny0=0.f,nxy0=0.f,nxx0=0.f;
                float nx1=0.f,ny1=0.f,nxy1=0.f,nxx1=0.f;
                float4 tap;
#pragma unroll
                for (int d = 0; d < 9; ++d) {
                    tap = xybuf[cur][t + d];
                    nx0 += tap.x; ny0 += tap.y; nxy0 += tap.x * tap.y; nxx0 += tap.x * tap.x;
                    nx1 += tap.z; ny1 += tap.w; nxy1 += tap.z * tap.w; nxx1 += tap.z * tap.z;
                }
                // tap==taps[8] is region col t+8 == output col c_abs
                xdel[s0] = tap.x;   // x(r0+8, c_abs)
                xdel[s1] = tap.z;   // x(r0+9, c_abs)

                // -- row0 vertical ring + A,b --
                vx  += nx0  - hx[s0];  hx[s0]  = nx0;
                vy  += ny0  - hy[s0];  hy[s0]  = ny0;
                vxy += nxy0 - hxy[s0]; hxy[s0] = nxy0;
                vxx += nxx0 - hxx[s0]; hxx[s0] = nxx0;
                float A0 = 0.f, B0 = 0.f;
                const int ra0 = r0 + 4;
                if (S >= 4 && a_colok && ra0 >= 0 && ra0 < H) {
                    const float invCh = 1.0f /
                        (float)(min(ra0 + RADIUS, H - 1) - max(ra0 - RADIUS, 0) + 1);
                    float invN = invCh * invCwA;
                    float mx = vx * invN, my = vy * invN;
                    float cov = vxy * invN - mx * my;
                    float vr  = vxx * invN - mx * mx;
                    A0 = cov * __builtin_amdgcn_rcpf(vr + 0.1f);
                    B0 = my - A0 * mx;
                }
                // -- row1 vertical ring + A,b --
                vx  += nx1  - hx[s1];  hx[s1]  = nx1;
                vy  += ny1  - hy[s1];  hy[s1]  = ny1;
                vxy += nxy1 - hxy[s1]; hxy[s1] = nxy1;
                vxx += nxx1 - hxx[s1]; hxx[s1] = nxx1;
                float A1 = 0.f, B1 = 0.f;
                const int ra1 = r0 + 5;
                if (S >= 4 && a_colok && ra1 >= 0 && ra1 < H) {
                    const float invCh = 1.0f /
                        (float)(min(ra1 + RADIUS, H - 1) - max(ra1 - RADIUS, 0) + 1);
                    float invN = invCh * invCwA;
                    float mx = vx * invN, my = vy * invN;
                    float cov = vxy * invN - mx * my;
                    float vr  = vxx * invN - mx * mx;
                    A1 = cov * __builtin_amdgcn_rcpf(vr + 0.1f);
                    B1 = my - A1 * mx;
                }
                if (S >= 4) abbuf[cur][t] = make_float4(A0, B0, A1, B1);

                // -- extra A-cols (region 260..267), lanes t<8, same-lane RMW ring --
                if (t < 8) {
                    float ex0=0.f,ey0=0.f,exy0=0.f,exx0=0.f;
                    float ex1=0.f,ey1=0.f,exy1=0.f,exx1=0.f;
#pragma unroll
                    for (int d = 0; d < 9; ++d) {
                        float4 v = xybuf[cur][256 + t + d];
                        ex0 += v.x; ey0 += v.y; exy0 += v.x * v.y; exx0 += v.x * v.x;
                        ex1 += v.z; ey1 += v.w; exy1 += v.z * v.w; exx1 += v.z * v.z;
                    }
                    float4 o0 = tring[s0][t];
                    v2x += ex0 - o0.x; v2y += ey0 - o0.y; v2xy += exy0 - o0.z; v2xx += exx0 - o0.w;
                    tring[s0][t] = make_float4(ex0, ey0, exy0, exx0);
                    float A20 = 0.f, B20 = 0.f;
                    if (S >= 4 && a2_colok && ra0 >= 0 && ra0 < H) {
                        const float invCh = 1.0f /
                            (float)(min(ra0 + RADIUS, H - 1) - max(ra0 - RADIUS, 0) + 1);
                        float invN = invCh * invCwA2;
                        float mx = v2x * invN, my = v2y * invN;
                        float cov = v2xy * invN - mx * my;
                        float vr  = v2xx * invN - mx * mx;
                        A20 = cov * __builtin_amdgcn_rcpf(vr + 0.1f);
                        B20 = my - A20 * mx;
                    }
                    float4 o1 = tring[s1][t];
                    v2x += ex1 - o1.x; v2y += ey1 - o1.y; v2xy += exy1 - o1.z; v2xx += exx1 - o1.w;
                    tring[s1][t] = make_float4(ex1, ey1, exy1, exx1);
                    float A21 = 0.f, B21 = 0.f;
                    if (S >= 4 && a2_colok && ra1 >= 0 && ra1 < H) {
                        const float invCh = 1.0f /
                            (float)(min(ra1 + RADIUS, H - 1) - max(ra1 - RADIUS, 0) + 1);
                        float invN = invCh * invCwA2;
                        float mx = v2x * invN, my = v2y * invN;
                        float cov = v2xy * invN - mx * my;
                        float vr  = v2xx * invN - mx * mx;
                        A21 = cov * __builtin_amdgcn_rcpf(vr + 0.1f);
                        B21 = my - A21 * mx;
                    }
                    if (S >= 4) abbuf[cur][256 + t] = make_float4(A20, B20, A21, B21);
                }

                __syncthreads();   // single barrier per step

                // -- O: 9 b128 taps of A,b -> both output rows --
                if (S >= 4) {
                    float hA0=0.f,hB0=0.f,hA1=0.f,hB1=0.f;
#pragma unroll
                    for (int d = 0; d < 9; ++d) {
                        float4 v = abbuf[cur][t + d];
                        hA0 += v.x; hB0 += v.y; hA1 += v.z; hB1 += v.w;
                    }
                    vA += hA0 - hA9[s0]; hA9[s0] = hA0;
                    vB += hB0 - hB9[s0]; hB9[s0] = hB0;
                    if (S >= 8) {
                        const float invCh = 1.0f /
                            (float)(min(r0 + RADIUS, H - 1) - max(r0 - RADIUS, 0) + 1);
                        float invN = invCh * invCwO;
                        op[r0 * W + c_abs] = (vA * invN) * xq0 + (vB * invN);
                    }
                    vA += hA1 - hA9[s1]; hA9[s1] = hA1;
                    vB += hB1 - hB9[s1]; hB9[s1] = hB1;
                    if (S >= 8) {
                        const int r = r0 + 1;
                        const float invCh = 1.0f /
                            (float)(min(r + RADIUS, H - 1) - max(r - RADIUS, 0) + 1);
                        float invN = invCh * invCwO;
                        op[r * W + c_abs] = (vA * invN) * xq1 + (vB * invN);
                    }
                }
            }
        }
    }
}

extern "C" void kernel_launch(void* const* d_in, const int* in_sizes, int n_in,
                              void* d_out, int out_size, void* d_ws, size_t ws_size,
                              hipStream_t stream) {
    const float* x = (const float*)d_in[0];
    const float* y = (const float*)d_in[1];
    float* out = (float*)d_out;

    dim3 grid(W / SW, H / ROWS, 24);   // 3 x 16 x 24 = 1152 blocks
    dim3 block(256);
    hipLaunchKernelGGL(gf_stream4, grid, block, 0, stream, x, y, out);
}